// Round 3
// baseline (1219.052 us; speedup 1.0000x reference)
//
#include <hip/hip_runtime.h>
#include <stdint.h>

typedef uint16_t u16;
typedef uint32_t u32;
typedef uint64_t u64;

#define TPB   256
#define TILE  2048      // scan/unzip granularity (TPB*8)
#define RADIX 512
#define RBITS 9
#define STILE 4096      // sort tile (2^12)
#define SSLOT 16        // STILE / TPB
#define WIN   8         // genK LDS histogram tile window

__device__ __forceinline__ int clampi(int v, int lo, int hi){ return v < lo ? lo : (v > hi ? hi : v); }

__device__ __forceinline__ u32 expand10(u32 x){
  x &= 1023u;
  x = (x | (x << 16)) & 0x030000FFu;
  x = (x | (x << 8))  & 0x0300F00Fu;
  x = (x | (x << 4))  & 0x030C30C3u;
  x = (x | (x << 2))  & 0x09249249u;
  return x;
}
__device__ __forceinline__ u32 morton3(int gx, int gy, int gz){
  u32 x = (u32)clampi(gx, 0, 1023);
  u32 y = (u32)clampi(gy, 0, 1023);
  u32 z = (u32)clampi(gz, 0, 1023);
  return (expand10(x) << 2) | (expand10(y) << 1) | expand10(z);
}

struct Box { int a0,a1,a2,e0,e1,e2,nv; };
__device__ __forceinline__ Box boxOf(int i, const float* mn, const float* mx,
                                     float g0, float g1, float g2, float vs, int gs){
  Box b;
  int a0 = clampi((int)floorf((mn[3*i+0] - g0) / vs), 0, gs-1);
  int a1 = clampi((int)floorf((mn[3*i+1] - g1) / vs), 0, gs-1);
  int a2 = clampi((int)floorf((mn[3*i+2] - g2) / vs), 0, gs-1);
  int b0 = clampi((int)floorf((mx[3*i+0] - g0) / vs), 0, gs-1);
  int b1 = clampi((int)floorf((mx[3*i+1] - g1) / vs), 0, gs-1);
  int b2 = clampi((int)floorf((mx[3*i+2] - g2) / vs), 0, gs-1);
  b.a0=a0; b.a1=a1; b.a2=a2;
  b.e0=b0-a0+1; b.e1=b1-a1+1; b.e2=b2-a2+1;
  b.nv = b.e0*b.e1*b.e2;
  return b;
}

__global__ void countK(const float* mn, const float* mx, const float* gmin,
                       const float* vs_p, const int* gs_p, const int* T_p,
                       u32* counts, int* out_ovr, int M){
  int i = blockIdx.x * TPB + threadIdx.x;
  if (i >= M) return;
  float vs = vs_p[0]; int gs = gs_p[0]; int T = T_p[0];
  Box b = boxOf(i, mn, mx, gmin[0], gmin[1], gmin[2], vs, gs);
  int ovr = b.nv > T;
  counts[i] = ovr ? 0u : (u32)b.nv;
  out_ovr[i] = ovr;
}

__global__ void scanAK(const u32* counts, int* out_off, u32* blockSums, int M){
  __shared__ u32 s[TPB];
  int b = blockIdx.x, t = threadIdx.x;
  int base = b * TILE + t * 8;
  u32 incl[8]; u32 run = 0;
  #pragma unroll
  for (int j = 0; j < 8; ++j){
    int g = base + j;
    u32 v = (g < M) ? counts[g] : 0u;
    run += v; incl[j] = run;
  }
  s[t] = run;
  __syncthreads();
  for (int o = 1; o < TPB; o <<= 1){
    u32 x = (t >= o) ? s[t-o] : 0u;
    __syncthreads();
    s[t] += x;
    __syncthreads();
  }
  u32 tbase = s[t] - run;
  #pragma unroll
  for (int j = 0; j < 8; ++j){
    int g = base + j;
    if (g < M) out_off[g+1] = (int)(tbase + incl[j]);
  }
  if (t == TPB-1) blockSums[b] = s[TPB-1];
}

__global__ void scanBK(u32* blockSums, int nb){
  __shared__ u32 s[TPB];
  int t = threadIdx.x;
  u32 run = 0;
  int nch = (nb + TPB - 1) / TPB;
  for (int c = 0; c < nch; ++c){
    int i = c * TPB + t;
    u32 v = (i < nb) ? blockSums[i] : 0u;
    s[t] = v;
    __syncthreads();
    for (int o = 1; o < TPB; o <<= 1){
      u32 x = (t >= o) ? s[t-o] : 0u;
      __syncthreads();
      s[t] += x;
      __syncthreads();
    }
    if (i < nb) blockSums[i] = run + s[t] - v;
    u32 tot = s[TPB-1];
    __syncthreads();
    run += tot;
  }
}

__global__ void scanCK(int* out_off, const u32* blockSums, int M, int* out_total){
  int b = blockIdx.x, t = threadIdx.x;
  u32 add = blockSums[b];
  int base = b * TILE + t * 8;
  #pragma unroll
  for (int j = 0; j < 8; ++j){
    int g = base + j;
    if (g < M){
      int v = out_off[g+1] + (int)add;
      out_off[g+1] = v;
      if (g == M-1) out_total[0] = v;
    }
  }
  if (b == 0 && t == 0) out_off[0] = 0;
}

// generate packed (morton<<32 | sid); accumulate pass-0 per-tile hist (LDS window)
// and per-digit totals for all 3 passes.
__global__ void genK(const float* mn, const float* mx, const float* gmin,
                     const float* vs_p, const int* gs_p, const int* T_p,
                     const int* out_off, u64* out, u32* hist0, u32* digitTotalAll,
                     int maxTiles, int M){
  __shared__ u32 winHist[WIN * RADIX];   // 16 KB
  __shared__ u32 digTot[3 * RADIX];      // 6 KB
  __shared__ int stile0;
  int t = threadIdx.x;
  for (int i = t; i < WIN * RADIX; i += TPB) winHist[i] = 0;
  for (int i = t; i < 3 * RADIX; i += TPB) digTot[i] = 0;
  if (t == 0) stile0 = out_off[blockIdx.x * TPB] >> 12;
  __syncthreads();
  int tile0 = stile0;
  int i = blockIdx.x * TPB + t;
  if (i < M){
    float vs = vs_p[0]; int gs = gs_p[0]; int T = T_p[0];
    Box b = boxOf(i, mn, mx, gmin[0], gmin[1], gmin[2], vs, gs);
    if (b.nv <= T){
      int base = out_off[i];
      int k = 0;
      for (int dx = 0; dx < b.e0; ++dx)
        for (int dy = 0; dy < b.e1; ++dy)
          for (int dz = 0; dz < b.e2; ++dz){
            u32 m = morton3(b.a0 + dx, b.a1 + dy, b.a2 + dz);
            int pos = base + k; ++k;
            out[pos] = ((u64)m << 32) | (u32)i;
            u32 d0 = m & (RADIX-1), d1 = (m >> RBITS) & (RADIX-1), d2 = m >> (2*RBITS);
            atomicAdd(&digTot[d0], 1u);
            atomicAdd(&digTot[RADIX + d1], 1u);
            atomicAdd(&digTot[2*RADIX + d2], 1u);
            int rel = (pos >> 12) - tile0;
            if (rel >= 0 && rel < WIN) atomicAdd(&winHist[(rel << 9) + d0], 1u);
            else atomicAdd(&hist0[(size_t)d0 * maxTiles + (pos >> 12)], 1u);
          }
    }
  }
  __syncthreads();
  for (int idx = t; idx < WIN * RADIX; idx += TPB){
    u32 c = winHist[idx];
    if (c){
      int w = idx >> 9, d = idx & (RADIX-1);
      atomicAdd(&hist0[(size_t)d * maxTiles + (tile0 + w)], c);
    }
  }
  for (int idx = t; idx < 3 * RADIX; idx += TPB){
    u32 c = digTot[idx];
    if (c) atomicAdd(&digitTotalAll[idx], c);
  }
}

// exclusive scan of the three 512-digit totals
__global__ void digitScanAllK(const u32* digitTotalAll, u32* digitBaseAll){
  __shared__ u32 s[RADIX];
  int t = threadIdx.x;
  for (int p = 0; p < 3; ++p){
    u32 v = digitTotalAll[p*RADIX + t];
    s[t] = v;
    __syncthreads();
    for (int o = 1; o < RADIX; o <<= 1){
      u32 x = (t >= o) ? s[t-o] : 0u;
      __syncthreads();
      s[t] += x;
      __syncthreads();
    }
    digitBaseAll[p*RADIX + t] = s[t] - v;
    __syncthreads();
  }
}

// per-digit running prefix over tiles (in place), base 0
__global__ void tileScanK(u32* hist, const int* total_p, int maxTiles){
  __shared__ u32 s[TPB];
  int d = blockIdx.x, t = threadIdx.x;
  int total = *total_p;
  int numTiles = (total + STILE - 1) / STILE;
  u32 running = 0;
  int nch = (numTiles + TPB - 1) / TPB;
  for (int c = 0; c < nch; ++c){
    int i = c * TPB + t;
    u32 v = (i < numTiles) ? hist[(size_t)d * maxTiles + i] : 0u;
    s[t] = v;
    __syncthreads();
    for (int o = 1; o < TPB; o <<= 1){
      u32 x = (t >= o) ? s[t-o] : 0u;
      __syncthreads();
      s[t] += x;
      __syncthreads();
    }
    if (i < numTiles) hist[(size_t)d * maxTiles + i] = running + s[t] - v;
    u32 tot = s[TPB-1];
    __syncthreads();
    running += tot;
  }
}

// staged scatter via LDS inverse-permutation (no register element arrays).
// Also accumulates next-pass per-tile histogram on write destinations.
__global__ void scatterK(const u64* __restrict__ in, u64* __restrict__ out,
                         const u32* __restrict__ histP, const u32* __restrict__ digitBaseP,
                         u32* histNext, const int* total_p, int maxTiles,
                         int shift, int nextShift){
  __shared__ u64 lin[STILE];        // 32 KB
  __shared__ u16 wHist[4 * RADIX];  // 4 KB  [wave][digit]
  __shared__ u16 ridx[STILE];       // 8 KB  rank -> local index
  __shared__ u32 startS[RADIX];     // 2 KB  tile-local digit starts
  __shared__ u32 baseS[RADIX];      // 2 KB  global digit bases for this tile
  __shared__ u32 tmp[TPB];          // 1 KB

  int tile = blockIdx.x, t = threadIdx.x;
  int total = *total_p;
  int numTiles = (total + STILE - 1) / STILE;
  if (tile >= numTiles) return;
  int lane = t & 63, wave = t >> 6;
  u64 lt = (1ull << lane) - 1ull;

  for (int i = t; i < 4 * RADIX; i += TPB) wHist[i] = 0;
  for (int d = t; d < RADIX; d += TPB)
    baseS[d] = digitBaseP[d] + histP[(size_t)d * maxTiles + tile];
  __syncthreads();

  int tbase = tile * STILE;
  int cbase = tbase + (wave << 10);
  u16* wh = &wHist[wave << 9];

  u32 rrd[SSLOT];   // (rankInWave<<16) | digit — static indices only

  #pragma unroll
  for (int s = 0; s < SSLOT; ++s){
    int idx = cbase + (s << 6) + lane;
    bool valid = idx < total;
    u64 e = valid ? in[idx] : 0ull;
    lin[idx - tbase] = e;
    int d = (int)(((u32)(e >> 32)) >> shift) & (RADIX - 1);
    u64 mask = __ballot(valid);
    #pragma unroll
    for (int b = 0; b < RBITS; ++b){
      u64 bal = __ballot((d >> b) & 1);
      mask &= ((d >> b) & 1) ? bal : ~bal;
    }
    u32 lr = (u32)__popcll(mask & lt);
    u32 old = valid ? (u32)wh[d] : 0u;
    if (valid && ((mask & lt) == 0ull)) wh[d] = (u16)(old + (u32)__popcll(mask));
    rrd[s] = ((old + lr) << 16) | (u32)d;
  }
  __syncthreads();

  for (int d = t; d < RADIX; d += TPB){
    u32 c0 = wHist[d], c1 = wHist[RADIX + d], c2 = wHist[2*RADIX + d], c3 = wHist[3*RADIX + d];
    wHist[d] = 0; wHist[RADIX + d] = (u16)c0;
    wHist[2*RADIX + d] = (u16)(c0 + c1); wHist[3*RADIX + d] = (u16)(c0 + c1 + c2);
    startS[d] = c0 + c1 + c2 + c3;
  }
  __syncthreads();
  u32 a0 = startS[2*t], a1 = startS[2*t + 1];
  u32 sum = a0 + a1;
  tmp[t] = sum;
  __syncthreads();
  for (int o = 1; o < TPB; o <<= 1){
    u32 x = (t >= o) ? tmp[t-o] : 0u;
    __syncthreads();
    tmp[t] += x;
    __syncthreads();
  }
  u32 excl = tmp[t] - sum;
  startS[2*t] = excl;
  startS[2*t + 1] = excl + a0;
  __syncthreads();

  #pragma unroll
  for (int s = 0; s < SSLOT; ++s){
    int idx = cbase + (s << 6) + lane;
    if (idx < total){
      u32 rd = rrd[s];
      u32 d = rd & (RADIX - 1);
      u32 pos = startS[d] + (u32)wh[d] + (rd >> 16);
      ridx[pos] = (u16)(idx - tbase);
    }
  }
  __syncthreads();

  int tileElems = total - tbase; if (tileElems > STILE) tileElems = STILE;
  if (histNext){
    for (int j = t; j < tileElems; j += TPB){
      u64 e = lin[ridx[j]];
      u32 key = (u32)(e >> 32);
      int d = (int)((key >> shift) & (RADIX - 1));
      int dest = (int)(baseS[d] + (u32)j - startS[d]);
      out[dest] = e;
      int nd = (int)((key >> nextShift) & (RADIX - 1));
      atomicAdd(&histNext[(size_t)nd * maxTiles + (dest >> 12)], 1u);
    }
  } else {
    for (int j = t; j < tileElems; j += TPB){
      u64 e = lin[ridx[j]];
      u32 key = (u32)(e >> 32);
      int d = (int)((key >> shift) & (RADIX - 1));
      int dest = (int)(baseS[d] + (u32)j - startS[d]);
      out[dest] = e;
    }
  }
}

// unzip sorted packed buffer + tail fill, fully coalesced
__global__ void unzipTailK(const u64* __restrict__ buf, int* out_m, int* out_s,
                           const int* total_p, int MT){
  int total = *total_p;
  int base = blockIdx.x * TILE + threadIdx.x;
  #pragma unroll
  for (int s = 0; s < TILE / TPB; ++s){
    int j = base + s * TPB;
    if (j < MT){
      if (j < total){
        u64 e = buf[j];
        out_m[j] = (int)(u32)(e >> 32);
        out_s[j] = (int)(u32)e;
      } else {
        out_m[j] = 0;
        out_s[j] = -1;
      }
    }
  }
}

extern "C" void kernel_launch(void* const* d_in, const int* in_sizes, int n_in,
                              void* d_out, int out_size, void* d_ws, size_t ws_size,
                              hipStream_t stream){
  const float* mn   = (const float*)d_in[0];
  const float* mx   = (const float*)d_in[1];
  const float* gmin = (const float*)d_in[2];
  const float* vs   = (const float*)d_in[3];
  const int*   gs   = (const int*)d_in[4];
  const int*   T_p  = (const int*)d_in[5];

  int M = in_sizes[0] / 3;
  long long S = (long long)out_size - 2LL*M - 2LL;
  int T = (int)(S / (2LL*M));
  int MT = (int)((long long)M * T);

  int* out_m     = (int*)d_out;
  int* out_s     = out_m + MT;
  int* out_off   = out_s + MT;
  int* out_ovr   = out_off + (M + 1);
  int* out_total = out_ovr + M;

  uint8_t* w = (uint8_t*)d_ws;
  size_t off = 0;
  auto alloc = [&](size_t bytes) -> void* {
    size_t p = (off + 255) & ~(size_t)255;
    off = p + bytes;
    return (void*)(w + p);
  };
  int nbA = (M + TILE - 1) / TILE;
  u32* counts       = (u32*)alloc((size_t)M * 4);
  u32* blockSums    = (u32*)alloc((size_t)nbA * 4);
  u32* digitBaseAll = (u32*)alloc(3 * RADIX * 4);

  size_t fixed = off + 8192;
  size_t avail = ws_size > fixed ? ws_size - fixed : 0;
  long long cap = (long long)(avail / 10) & ~(long long)(STILE - 1);  // 8B buf + 3*0.5B hist per elem
  if (cap > MT) cap = MT;
  if (cap < STILE) cap = STILE;
  int maxTiles = (int)(cap / STILE);

  size_t histSz = (size_t)RADIX * maxTiles * 4;
  uint8_t* zeroRegion = (uint8_t*)alloc(3 * histSz + 3 * RADIX * 4);
  u32* hist0        = (u32*)zeroRegion;
  u32* hist1        = (u32*)(zeroRegion + histSz);
  u32* hist2        = (u32*)(zeroRegion + 2 * histSz);
  u32* digitTotalAll= (u32*)(zeroRegion + 3 * histSz);
  u64* bufA = (u64*)alloc((size_t)cap * 8);

  u64* bufB = (u64*)d_out;   // packed u64 region: bytes [0, 8*total) <= 8*MT

  int gM = (M + TPB - 1) / TPB;

  hipMemsetAsync(zeroRegion, 0, 3 * histSz + 3 * RADIX * 4, stream);
  countK<<<gM, TPB, 0, stream>>>(mn, mx, gmin, vs, gs, T_p, counts, out_ovr, M);
  scanAK<<<nbA, TPB, 0, stream>>>(counts, out_off, blockSums, M);
  scanBK<<<1, TPB, 0, stream>>>(blockSums, nbA);
  scanCK<<<nbA, TPB, 0, stream>>>(out_off, blockSums, M, out_total);
  genK<<<gM, TPB, 0, stream>>>(mn, mx, gmin, vs, gs, T_p, out_off, bufB, hist0, digitTotalAll, maxTiles, M);
  digitScanAllK<<<1, RADIX, 0, stream>>>(digitTotalAll, digitBaseAll);

  // pass 0: B(d_out) -> A, accumulate hist1
  tileScanK<<<RADIX, TPB, 0, stream>>>(hist0, out_total, maxTiles);
  scatterK<<<maxTiles, TPB, 0, stream>>>(bufB, bufA, hist0, digitBaseAll + 0*RADIX, hist1,
                                         out_total, maxTiles, 0, RBITS);
  // pass 1: A -> B, accumulate hist2
  tileScanK<<<RADIX, TPB, 0, stream>>>(hist1, out_total, maxTiles);
  scatterK<<<maxTiles, TPB, 0, stream>>>(bufA, bufB, hist1, digitBaseAll + 1*RADIX, hist2,
                                         out_total, maxTiles, RBITS, 2*RBITS);
  // pass 2: B -> A (packed final)
  tileScanK<<<RADIX, TPB, 0, stream>>>(hist2, out_total, maxTiles);
  scatterK<<<maxTiles, TPB, 0, stream>>>(bufB, bufA, hist2, digitBaseAll + 2*RADIX, nullptr,
                                         out_total, maxTiles, 2*RBITS, 0);
  // unzip + tail fill
  unzipTailK<<<(MT + TILE - 1) / TILE, TPB, 0, stream>>>(bufA, out_m, out_s, out_total, MT);
}